// Round 4
// baseline (515.861 us; speedup 1.0000x reference)
//
#include <hip/hip_runtime.h>
#include <hip/hip_bf16.h>

// Problem constants: B=32, S=512, D=256, H=8, DH=32
#define SCALE_QK 0.17677669529663687f  // 1/sqrt(32)

typedef __attribute__((ext_vector_type(8))) short short8;  // 8 bf16 (4 VGPRs)
typedef __attribute__((ext_vector_type(4))) float f32x4;

__device__ __forceinline__ ushort f2bf(float f) {  // fp32 -> bf16 RNE
  unsigned u = __float_as_uint(f);
  return (ushort)((u + 0x7FFF + ((u >> 16) & 1)) >> 16);
}

// C[m,n] = sum_k A[m,k]*W[n,k] + bias[n];  M=16384, N=256, K=256
// mode 0: C fp32 row-major [m][n]
// mode 1: C bf16 in q/k layout [b,h,s,e] (b=m>>9,s=m&511,h=n>>5,e=n&31),
//         value scaled by `scale` before rounding.
__global__ __launch_bounds__(256) void gemm_proj(const float *__restrict__ A,
                                                 const float *__restrict__ W,
                                                 const float *__restrict__ bias,
                                                 void *__restrict__ Cout,
                                                 int mode, float scale) {
  __shared__ float As[16][68];
  __shared__ float Ws[16][68];
  const int tid = threadIdx.x;
  const int m0 = blockIdx.x * 64;
  const int n0 = blockIdx.y * 64;
  const int ty = tid >> 4, tx = tid & 15;
  const int lm = tid >> 2, lk4 = (tid & 3) * 4;
  const float *Ald = A + (m0 + lm) * 256 + lk4;
  const float *Wld = W + (n0 + lm) * 256 + lk4;
  float acc[4][4] = {};
  for (int k0 = 0; k0 < 256; k0 += 16) {
    const float4 av = *(const float4 *)(Ald + k0);
    const float4 wv = *(const float4 *)(Wld + k0);
    __syncthreads();
    As[lk4 + 0][lm] = av.x; As[lk4 + 1][lm] = av.y;
    As[lk4 + 2][lm] = av.z; As[lk4 + 3][lm] = av.w;
    Ws[lk4 + 0][lm] = wv.x; Ws[lk4 + 1][lm] = wv.y;
    Ws[lk4 + 2][lm] = wv.z; Ws[lk4 + 3][lm] = wv.w;
    __syncthreads();
#pragma unroll
    for (int kk = 0; kk < 16; ++kk) {
      const float4 a = *(const float4 *)&As[kk][ty * 4];
      const float4 w = *(const float4 *)&Ws[kk][tx * 4];
      const float ar[4] = {a.x, a.y, a.z, a.w};
      const float wr[4] = {w.x, w.y, w.z, w.w};
#pragma unroll
      for (int r = 0; r < 4; ++r)
#pragma unroll
        for (int c = 0; c < 4; ++c) acc[r][c] += ar[r] * wr[c];
    }
  }
  const float4 bs = *(const float4 *)(bias + n0 + tx * 4);
  const float br[4] = {bs.x, bs.y, bs.z, bs.w};
#pragma unroll
  for (int r = 0; r < 4; ++r) {
    const int m = m0 + ty * 4 + r;
    float o[4];
#pragma unroll
    for (int c = 0; c < 4; ++c) o[c] = acc[r][c] + br[c];
    if (mode == 0) {
      *(float4 *)((float *)Cout + m * 256 + n0 + tx * 4) =
          make_float4(o[0], o[1], o[2], o[3]);
    } else {
      const int b = m >> 9, s = m & 511;
      const int n = n0 + tx * 4, h = n >> 5, e = n & 31;
      ushort4 o4;
      o4.x = f2bf(o[0] * scale); o4.y = f2bf(o[1] * scale);
      o4.z = f2bf(o[2] * scale); o4.w = f2bf(o[3] * scale);
      *(ushort4 *)((ushort *)Cout + (((b << 3) + h) * 512 + s) * 32 + e) = o4;
    }
  }
}

// Fused scores (MFMA bf16) + diag-mask + sparsemax + head-average.
// Q (pre-scaled by 1/sqrt(32)) and K are bf16 [B,H,S,32].
// One wave per block; wave owns 16 q-rows x all 512 cols.
// MFMA 16x16x32: A-frag = Q rows (m=lane&15, k=quad*8+j), B-frag = K rows
// (n=lane&15, k=quad*8+j) -> both direct 16B row loads. C/D layout:
// col = j*16 + (lane&15), row = s0 + quad*4 + reg.
//
// Sparsemax (exact, LDS-free): tau* >= M-1 (M = row max) since max - tau* <=
// sum(z-tau*)=1. Michelot iteration started at threshold M-1 keeps every
// support element (all thresholds <= tau*) and converges when the support
// count stabilizes; then tau = (sum-1)/cnt is exact. Counts via masked
// __ballot/popcll (SALU, full-exec), sums via intra-quad shfl_xor. tau[r]
// naturally lives in the same lanes as acc[j][r] -> no broadcast needed.
// No LDS, no barriers, no atomics, uniform control flow at cross-lane ops.
__global__ __launch_bounds__(64, 1) void attn_sparsemax_mfma(
    const ushort *__restrict__ Q, const ushort *__restrict__ K,
    float *__restrict__ avg) {
  const int lane = threadIdx.x;
  const int quad = lane >> 4, l15 = lane & 15;
  const int s0 = blockIdx.x * 16;
  const int j0 = blockIdx.x;  // score tile containing this row block's diagonal
  const int b = blockIdx.y;
  const unsigned long long qm = 0xFFFFull << (quad * 16);

  float avgacc[32][4] = {};
#pragma unroll 1
  for (int h = 0; h < 8; ++h) {
    const ushort *qh = Q + (((b << 3) + h) * 512 + s0) * 32;
    const ushort *kh = K + ((b << 3) + h) * 512 * 32;
    const short8 aq = *(const short8 *)(qh + l15 * 32 + quad * 8);
    f32x4 acc[32];
#pragma unroll
    for (int j = 0; j < 32; ++j) {
      const short8 bk = *(const short8 *)(kh + (j * 16 + l15) * 32 + quad * 8);
      acc[j] = __builtin_amdgcn_mfma_f32_16x16x32_bf16(
          aq, bk, (f32x4){0.f, 0.f, 0.f, 0.f}, 0, 0, 0);
    }
    // diagonal mask: col j*16+l15 == row s0+quad*4+r <=> j==j0 && l15==quad*4+r
#pragma unroll
    for (int r = 0; r < 4; ++r) {
      if (l15 == quad * 4 + r) acc[j0][r] = -1e30f;
    }
    // per-row max -> initial threshold M-1
    float tau[4];
#pragma unroll
    for (int r = 0; r < 4; ++r) {
      float mm = acc[0][r];
#pragma unroll
      for (int j = 1; j < 32; ++j) mm = fmaxf(mm, acc[j][r]);
      mm = fmaxf(mm, __shfl_xor(mm, 1, 64));
      mm = fmaxf(mm, __shfl_xor(mm, 2, 64));
      mm = fmaxf(mm, __shfl_xor(mm, 4, 64));
      mm = fmaxf(mm, __shfl_xor(mm, 8, 64));
      tau[r] = mm - 1.0f;
    }
    // Michelot: scan register scores; stop when all 4 row supports stable
    int cold[4] = {-1, -1, -1, -1};
#pragma unroll 1
    for (int it = 0; it < 32; ++it) {
      float sm[4];
      int nc[4];
#pragma unroll
      for (int r = 0; r < 4; ++r) {
        float s = 0.f;
        int c = 0;
#pragma unroll
        for (int j = 0; j < 32; ++j) {
          const bool p = acc[j][r] > tau[r];
          s += p ? acc[j][r] : 0.f;
          c += (int)__popcll(__ballot(p) & qm);
        }
        s += __shfl_xor(s, 1, 64);
        s += __shfl_xor(s, 2, 64);
        s += __shfl_xor(s, 4, 64);
        s += __shfl_xor(s, 8, 64);
        sm[r] = s;
        nc[r] = c;
      }
      const bool stable = nc[0] == cold[0] && nc[1] == cold[1] &&
                          nc[2] == cold[2] && nc[3] == cold[3];
      if (__all(stable)) break;  // support fixed -> tau exact
#pragma unroll
      for (int r = 0; r < 4; ++r) {
        if (nc[r] != cold[r]) {
          tau[r] = (sm[r] - 1.f) / (float)nc[r];
          cold[r] = nc[r];
        }
      }
    }
    // accumulate head-average (tau[r] is in the same lanes as acc[j][r])
#pragma unroll
    for (int r = 0; r < 4; ++r)
#pragma unroll
      for (int j = 0; j < 32; ++j)
        avgacc[j][r] += fmaxf(acc[j][r] - tau[r], 0.f);
  }
  // write avg (includes 1/H)
#pragma unroll
  for (int r = 0; r < 4; ++r) {
    const int s = s0 + quad * 4 + r;
    float *dst = avg + ((b * 512 + s) << 9) + l15;
#pragma unroll
    for (int j = 0; j < 32; ++j) dst[j * 16] = avgacc[j][r] * 0.125f;
  }
}

// Batched NN GEMM: C[b] = A[b] (512x512) * V[b] (512x256)
__global__ __launch_bounds__(256) void gemm_av(const float *__restrict__ A,
                                               const float *__restrict__ V,
                                               float *__restrict__ C) {
  __shared__ float As[16][68];
  __shared__ float Bs[16][68];
  const int tid = threadIdx.x;
  const int b = blockIdx.z;
  const int m0 = blockIdx.x * 64, n0 = blockIdx.y * 64;
  const float *Ab = A + b * 512 * 512;
  const float *Vb = V + b * 512 * 256;
  float *Cb = C + b * 512 * 256;
  const int ty = tid >> 4, tx = tid & 15;
  const int lm = tid >> 2, lk4 = (tid & 3) * 4;
  const int lkb = tid >> 4, lnb = (tid & 15) * 4;
  float acc[4][4] = {};
  for (int k0 = 0; k0 < 512; k0 += 16) {
    const float4 av = *(const float4 *)(Ab + (m0 + lm) * 512 + k0 + lk4);
    const float4 bv = *(const float4 *)(Vb + (k0 + lkb) * 256 + n0 + lnb);
    __syncthreads();
    As[lk4 + 0][lm] = av.x; As[lk4 + 1][lm] = av.y;
    As[lk4 + 2][lm] = av.z; As[lk4 + 3][lm] = av.w;
    *(float4 *)&Bs[lkb][lnb] = bv;
    __syncthreads();
#pragma unroll
    for (int kk = 0; kk < 16; ++kk) {
      const float4 a = *(const float4 *)&As[kk][ty * 4];
      const float4 w = *(const float4 *)&Bs[kk][tx * 4];
      const float ar[4] = {a.x, a.y, a.z, a.w};
      const float wr[4] = {w.x, w.y, w.z, w.w};
#pragma unroll
      for (int r = 0; r < 4; ++r)
#pragma unroll
        for (int c = 0; c < 4; ++c) acc[r][c] += ar[r] * wr[c];
    }
  }
#pragma unroll
  for (int r = 0; r < 4; ++r) {
    float4 o;
    o.x = acc[r][0]; o.y = acc[r][1]; o.z = acc[r][2]; o.w = acc[r][3];
    *(float4 *)(Cb + (m0 + ty * 4 + r) * 256 + n0 + tx * 4) = o;
  }
}

extern "C" void kernel_launch(void* const* d_in, const int* in_sizes, int n_in,
                              void* d_out, int out_size, void* d_ws, size_t ws_size,
                              hipStream_t stream) {
  const float *x  = (const float *)d_in[0];
  const float *Wq = (const float *)d_in[1];
  const float *bq = (const float *)d_in[2];
  const float *Wk = (const float *)d_in[3];
  const float *bk = (const float *)d_in[4];
  const float *Wv = (const float *)d_in[5];
  const float *bv = (const float *)d_in[6];
  const float *Wo = (const float *)d_in[7];
  const float *bo = (const float *)d_in[8];

  float *out = (float *)d_out;                 // [B,S,D]
  float *avg = out + 32 * 512 * 256;           // [B,S,S]

  // workspace (peak 32 MB): qbf 8MB | kbf 8MB | v 16MB ; mid reuses qbf+kbf
  ushort *qbf = (ushort *)d_ws;                // [B,H,S,32] bf16 (pre-scaled)
  ushort *kbf = qbf + 32 * 8 * 512 * 32;       // [B,H,S,32] bf16
  float  *v   = (float *)(kbf + 32 * 8 * 512 * 32);  // [B,S,256] fp32
  float  *mid = (float *)d_ws;                 // [B,S,256] fp32 (after attn)

  const dim3 blk(256);
  const dim3 gProj(256, 4);

  gemm_proj<<<gProj, blk, 0, stream>>>(x, Wq, bq, qbf, 1, SCALE_QK);
  gemm_proj<<<gProj, blk, 0, stream>>>(x, Wk, bk, kbf, 1, 1.0f);
  attn_sparsemax_mfma<<<dim3(32, 32), dim3(64), 0, stream>>>(qbf, kbf, avg);
  gemm_proj<<<gProj, blk, 0, stream>>>(x, Wv, bv, v, 0, 1.0f);
  gemm_av<<<dim3(8, 4, 32), blk, 0, stream>>>(avg, v, mid);
  gemm_proj<<<gProj, blk, 0, stream>>>(mid, Wo, bo, out, 0, 1.0f);
}

// Round 5
// 503.160 us; speedup vs baseline: 1.0252x; 1.0252x over previous
//
#include <hip/hip_runtime.h>
#include <hip/hip_bf16.h>

// Problem constants: B=32, S=512, D=256, H=8, DH=32
#define SCALE_QK 0.17677669529663687f  // 1/sqrt(32)

typedef __attribute__((ext_vector_type(8))) short short8;  // 8 bf16 (4 VGPRs)
typedef __attribute__((ext_vector_type(4))) float f32x4;

__device__ __forceinline__ ushort f2bf(float f) {  // fp32 -> bf16 RNE
  unsigned u = __float_as_uint(f);
  return (ushort)((u + 0x7FFF + ((u >> 16) & 1)) >> 16);
}

// C[m,n] = sum_k A[m,k]*W[n,k] + bias[n];  M=16384, N=256, K=256
// mode 0: C fp32 row-major [m][n]
// mode 1: C bf16 in q/k layout [b,h,s,e] (b=m>>9,s=m&511,h=n>>5,e=n&31),
//         value scaled by `scale` before rounding.
__global__ __launch_bounds__(256) void gemm_proj(const float *__restrict__ A,
                                                 const float *__restrict__ W,
                                                 const float *__restrict__ bias,
                                                 void *__restrict__ Cout,
                                                 int mode, float scale) {
  __shared__ float As[16][68];
  __shared__ float Ws[16][68];
  const int tid = threadIdx.x;
  const int m0 = blockIdx.x * 64;
  const int n0 = blockIdx.y * 64;
  const int ty = tid >> 4, tx = tid & 15;
  const int lm = tid >> 2, lk4 = (tid & 3) * 4;
  const float *Ald = A + (m0 + lm) * 256 + lk4;
  const float *Wld = W + (n0 + lm) * 256 + lk4;
  float acc[4][4] = {};
  for (int k0 = 0; k0 < 256; k0 += 16) {
    const float4 av = *(const float4 *)(Ald + k0);
    const float4 wv = *(const float4 *)(Wld + k0);
    __syncthreads();
    As[lk4 + 0][lm] = av.x; As[lk4 + 1][lm] = av.y;
    As[lk4 + 2][lm] = av.z; As[lk4 + 3][lm] = av.w;
    Ws[lk4 + 0][lm] = wv.x; Ws[lk4 + 1][lm] = wv.y;
    Ws[lk4 + 2][lm] = wv.z; Ws[lk4 + 3][lm] = wv.w;
    __syncthreads();
#pragma unroll
    for (int kk = 0; kk < 16; ++kk) {
      const float4 a = *(const float4 *)&As[kk][ty * 4];
      const float4 w = *(const float4 *)&Ws[kk][tx * 4];
      const float ar[4] = {a.x, a.y, a.z, a.w};
      const float wr[4] = {w.x, w.y, w.z, w.w};
#pragma unroll
      for (int r = 0; r < 4; ++r)
#pragma unroll
        for (int c = 0; c < 4; ++c) acc[r][c] += ar[r] * wr[c];
    }
  }
  const float4 bs = *(const float4 *)(bias + n0 + tx * 4);
  const float br[4] = {bs.x, bs.y, bs.z, bs.w};
#pragma unroll
  for (int r = 0; r < 4; ++r) {
    const int m = m0 + ty * 4 + r;
    float o[4];
#pragma unroll
    for (int c = 0; c < 4; ++c) o[c] = acc[r][c] + br[c];
    if (mode == 0) {
      *(float4 *)((float *)Cout + m * 256 + n0 + tx * 4) =
          make_float4(o[0], o[1], o[2], o[3]);
    } else {
      const int b = m >> 9, s = m & 511;
      const int n = n0 + tx * 4, h = n >> 5, e = n & 31;
      ushort4 o4;
      o4.x = f2bf(o[0] * scale); o4.y = f2bf(o[1] * scale);
      o4.z = f2bf(o[2] * scale); o4.w = f2bf(o[3] * scale);
      *(ushort4 *)((ushort *)Cout + (((b << 3) + h) * 512 + s) * 32 + e) = o4;
    }
  }
}

// Fused scores (MFMA bf16) + diag-mask + sparsemax + head-average.
// Q (pre-scaled by 1/sqrt(32)) and K are bf16 [B,H,S,32].
// Block = 256 threads = 4 waves, all on the same 16 q-rows; wave w owns
// column tiles 8w..8w+7 (128 cols) -> per-lane state is acc[8][4]+avgacc[8][4]
// = 64 floats (NO scratch spills; R4's single-wave version kept 256 floats
// live and spilled ~500 MB of scratch traffic = the whole runtime).
// MFMA 16x16x32: A-frag = Q rows, B-frag = K rows (both direct 16B loads).
// C/D: col = jg*16 + (lane&15), row = s0 + quad*4 + reg.
// Sparsemax: tau* >= M-1 warm start (max-tau* <= sum(z-tau*)=1), Michelot on
// register scores; per-row (sum,count) combined across waves via a tiny LDS
// partial array; convergence predicate computed identically in all waves from
// shared data -> uniform break, barrier-safe.
__global__ __launch_bounds__(256) void attn_sparsemax_mfma(
    const ushort *__restrict__ Q, const ushort *__restrict__ K,
    float *__restrict__ avg) {
  __shared__ float redmax[4][16];  // [wave][row]
  __shared__ float redsum[4][16];
  __shared__ float redcnt[4][16];
  const int tid = threadIdx.x;
  const int w = tid >> 6, lane = tid & 63;
  const int quad = lane >> 4, l15 = lane & 15;
  const int s0 = blockIdx.x * 16;
  const int j0 = blockIdx.x;  // global col tile holding this row block's diag
  const int b = blockIdx.y;
  const unsigned long long qm = 0xFFFFull << (quad * 16);
  const int jw0 = w * 8;  // first global col tile of this wave

  float avgacc[8][4] = {};
#pragma unroll 1
  for (int h = 0; h < 8; ++h) {
    const ushort *qh = Q + (((b << 3) + h) * 512 + s0) * 32;
    const ushort *kh = K + ((b << 3) + h) * 512 * 32;
    const short8 aq = *(const short8 *)(qh + l15 * 32 + quad * 8);
    f32x4 acc[8];
#pragma unroll
    for (int jl = 0; jl < 8; ++jl) {
      const short8 bk =
          *(const short8 *)(kh + ((jw0 + jl) * 16 + l15) * 32 + quad * 8);
      acc[jl] = __builtin_amdgcn_mfma_f32_16x16x32_bf16(
          aq, bk, (f32x4){0.f, 0.f, 0.f, 0.f}, 0, 0, 0);
    }
    // diagonal mask: col jg*16+l15 == row s0+quad*4+r
    if ((j0 >> 3) == w) {
      const int jl = j0 & 7;
#pragma unroll
      for (int r = 0; r < 4; ++r)
        if (l15 == quad * 4 + r) acc[jl][r] = -1e30f;
    }
    // per-row partial max over this wave's 128 cols
    float mm[4];
#pragma unroll
    for (int r = 0; r < 4; ++r) {
      float m = acc[0][r];
#pragma unroll
      for (int jl = 1; jl < 8; ++jl) m = fmaxf(m, acc[jl][r]);
      m = fmaxf(m, __shfl_xor(m, 1, 64));
      m = fmaxf(m, __shfl_xor(m, 2, 64));
      m = fmaxf(m, __shfl_xor(m, 4, 64));
      m = fmaxf(m, __shfl_xor(m, 8, 64));
      mm[r] = m;
    }
    __syncthreads();  // prior head's LDS reads complete
    if (l15 == 0) {
#pragma unroll
      for (int r = 0; r < 4; ++r) redmax[w][quad * 4 + r] = mm[r];
    }
    __syncthreads();
    float tau[4];
#pragma unroll
    for (int r = 0; r < 4; ++r) {
      const int row = quad * 4 + r;
      tau[r] = fmaxf(fmaxf(redmax[0][row], redmax[1][row]),
                     fmaxf(redmax[2][row], redmax[3][row])) -
               1.0f;
    }
    // Michelot iterations (block-synchronized, uniform convergence)
    float cold[4] = {-1.f, -1.f, -1.f, -1.f};
#pragma unroll 1
    for (int it = 0; it < 32; ++it) {
      float sm[4], nc[4];
#pragma unroll
      for (int r = 0; r < 4; ++r) {
        float s = 0.f;
        int c = 0;
#pragma unroll
        for (int jl = 0; jl < 8; ++jl) {
          const bool p = acc[jl][r] > tau[r];
          s += p ? acc[jl][r] : 0.f;
          c += (int)__popcll(__ballot(p) & qm);
        }
        s += __shfl_xor(s, 1, 64);
        s += __shfl_xor(s, 2, 64);
        s += __shfl_xor(s, 4, 64);
        s += __shfl_xor(s, 8, 64);
        sm[r] = s;
        nc[r] = (float)c;
      }
      __syncthreads();  // previous iteration's partial reads complete
      if (l15 == 0) {
#pragma unroll
        for (int r = 0; r < 4; ++r) {
          redsum[w][quad * 4 + r] = sm[r];
          redcnt[w][quad * 4 + r] = nc[r];
        }
      }
      __syncthreads();
      bool stable = true;
#pragma unroll
      for (int r = 0; r < 4; ++r) {
        const int row = quad * 4 + r;
        const float S =
            ((redsum[0][row] + redsum[1][row]) + (redsum[2][row] + redsum[3][row]));
        const float C =
            ((redcnt[0][row] + redcnt[1][row]) + (redcnt[2][row] + redcnt[3][row]));
        if (C != cold[r]) {
          stable = false;
          tau[r] = (S - 1.f) / C;
          cold[r] = C;
        }
      }
      // `stable` is identical in every lane/wave (derived from shared data
      // and per-lane state that is row-replicated) -> uniform break.
      if (__syncthreads_count(!stable) == 0) break;
    }
    // accumulate head-average (tau[r] lives in the same lanes as acc[jl][r])
#pragma unroll
    for (int r = 0; r < 4; ++r)
#pragma unroll
      for (int jl = 0; jl < 8; ++jl)
        avgacc[jl][r] += fmaxf(acc[jl][r] - tau[r], 0.f);
  }
  // write avg (includes 1/H)
#pragma unroll
  for (int r = 0; r < 4; ++r) {
    const int s = s0 + quad * 4 + r;
    float *dst = avg + ((b * 512 + s) << 9) + jw0 * 16 + l15;
#pragma unroll
    for (int jl = 0; jl < 8; ++jl) dst[jl * 16] = avgacc[jl][r] * 0.125f;
  }
}

// Batched NN GEMM: C[b] = A[b] (512x512) * V[b] (512x256)
__global__ __launch_bounds__(256) void gemm_av(const float *__restrict__ A,
                                               const float *__restrict__ V,
                                               float *__restrict__ C) {
  __shared__ float As[16][68];
  __shared__ float Bs[16][68];
  const int tid = threadIdx.x;
  const int b = blockIdx.z;
  const int m0 = blockIdx.x * 64, n0 = blockIdx.y * 64;
  const float *Ab = A + b * 512 * 512;
  const float *Vb = V + b * 512 * 256;
  float *Cb = C + b * 512 * 256;
  const int ty = tid >> 4, tx = tid & 15;
  const int lm = tid >> 2, lk4 = (tid & 3) * 4;
  const int lkb = tid >> 4, lnb = (tid & 15) * 4;
  float acc[4][4] = {};
  for (int k0 = 0; k0 < 512; k0 += 16) {
    const float4 av = *(const float4 *)(Ab + (m0 + lm) * 512 + k0 + lk4);
    const float4 bv = *(const float4 *)(Vb + (k0 + lkb) * 256 + n0 + lnb);
    __syncthreads();
    As[lk4 + 0][lm] = av.x; As[lk4 + 1][lm] = av.y;
    As[lk4 + 2][lm] = av.z; As[lk4 + 3][lm] = av.w;
    *(float4 *)&Bs[lkb][lnb] = bv;
    __syncthreads();
#pragma unroll
    for (int kk = 0; kk < 16; ++kk) {
      const float4 a = *(const float4 *)&As[kk][ty * 4];
      const float4 w = *(const float4 *)&Bs[kk][tx * 4];
      const float ar[4] = {a.x, a.y, a.z, a.w};
      const float wr[4] = {w.x, w.y, w.z, w.w};
#pragma unroll
      for (int r = 0; r < 4; ++r)
#pragma unroll
        for (int c = 0; c < 4; ++c) acc[r][c] += ar[r] * wr[c];
    }
  }
#pragma unroll
  for (int r = 0; r < 4; ++r) {
    float4 o;
    o.x = acc[r][0]; o.y = acc[r][1]; o.z = acc[r][2]; o.w = acc[r][3];
    *(float4 *)(Cb + (m0 + ty * 4 + r) * 256 + n0 + tx * 4) = o;
  }
}

extern "C" void kernel_launch(void* const* d_in, const int* in_sizes, int n_in,
                              void* d_out, int out_size, void* d_ws, size_t ws_size,
                              hipStream_t stream) {
  const float *x  = (const float *)d_in[0];
  const float *Wq = (const float *)d_in[1];
  const float *bq = (const float *)d_in[2];
  const float *Wk = (const float *)d_in[3];
  const float *bk = (const float *)d_in[4];
  const float *Wv = (const float *)d_in[5];
  const float *bv = (const float *)d_in[6];
  const float *Wo = (const float *)d_in[7];
  const float *bo = (const float *)d_in[8];

  float *out = (float *)d_out;                 // [B,S,D]
  float *avg = out + 32 * 512 * 256;           // [B,S,S]

  // workspace (peak 32 MB): qbf 8MB | kbf 8MB | v 16MB ; mid reuses qbf+kbf
  ushort *qbf = (ushort *)d_ws;                // [B,H,S,32] bf16 (pre-scaled)
  ushort *kbf = qbf + 32 * 8 * 512 * 32;       // [B,H,S,32] bf16
  float  *v   = (float *)(kbf + 32 * 8 * 512 * 32);  // [B,S,256] fp32
  float  *mid = (float *)d_ws;                 // [B,S,256] fp32 (after attn)

  const dim3 blk(256);
  const dim3 gProj(256, 4);

  gemm_proj<<<gProj, blk, 0, stream>>>(x, Wq, bq, qbf, 1, SCALE_QK);
  gemm_proj<<<gProj, blk, 0, stream>>>(x, Wk, bk, kbf, 1, 1.0f);
  attn_sparsemax_mfma<<<dim3(32, 32), blk, 0, stream>>>(qbf, kbf, avg);
  gemm_proj<<<gProj, blk, 0, stream>>>(x, Wv, bv, v, 0, 1.0f);
  gemm_av<<<dim3(8, 4, 32), blk, 0, stream>>>(avg, v, mid);
  gemm_proj<<<gProj, blk, 0, stream>>>(mid, Wo, bo, out, 0, 1.0f);
}